// Round 2
// baseline (1468.596 us; speedup 1.0000x reference)
//
#include <hip/hip_runtime.h>
#include <hip/hip_bf16.h>

// ConvContract: torus 3x3 tensor conv, collapsed to combined-channel conv. fp32.
// Combined in-channels : 192  (cin<64 -> x0[cin]; cin>=64 -> x1[i=(cin-64)/2][t=(cin-64)&1])
// Combined out-channels: 192  (co<64  -> out0[co]; co>=64 -> out1[o=(co-64)/2][u=(co-64)&1])
// F[co][cin][tap] synthesized from w00/w01/w10/w11 x fil0/fil1/fil2.
// Epilogue: out0 += b0 ; out1 += mean_yx(out1) * b1.

#define NN 256
#define NPIX 65536          // 256*256
#define COUT 192
#define CIN 192
#define TAPS 9
#define OCG 16              // out-channels per block in conv kernel
#define OUT1_OFF 4194304    // 64*256*256

// ---------------------------------------------------------------- synth ----
// F[co][cin][tap] (fp32) ; also zero the 128-entry mean accumulator.
__global__ void synth_kernel(const float* __restrict__ fil0, const float* __restrict__ fil1,
                             const float* __restrict__ fil2,
                             const float* __restrict__ w00, const float* __restrict__ w01,
                             const float* __restrict__ w10, const float* __restrict__ w11,
                             float* __restrict__ F, float* __restrict__ mean_acc) {
    int idx = blockIdx.x * 256 + threadIdx.x;
    if (blockIdx.x == 0 && threadIdx.x < 128) mean_acc[threadIdx.x] = 0.0f;
    if (idx >= COUT * CIN * TAPS) return;
    int tap = idx % 9;
    int cin = (idx / 9) % CIN;
    int co  = idx / (9 * CIN);
    float s = 0.0f;
    if (co < 64) {
        if (cin < 64) {
            for (int k = 0; k < 3; k++)              // w00[co][cin][k] * fil0[k][tap]
                s += w00[(co * 64 + cin) * 3 + k] * fil0[k * 9 + tap];
        } else {
            int i = (cin - 64) >> 1, t = (cin - 64) & 1;
            for (int k = 0; k < 6; k++)              // w10[co][i][k] * fil1[k][tap][t]
                s += w10[(co * 64 + i) * 6 + k] * fil1[(k * 9 + tap) * 2 + t];
        }
    } else {
        int o = (co - 64) >> 1, u = (co - 64) & 1;
        if (cin < 64) {
            for (int k = 0; k < 6; k++)              // w01[o][cin][k] * fil1[k][tap][u]
                s += w01[(o * 64 + cin) * 6 + k] * fil1[(k * 9 + tap) * 2 + u];
        } else {
            int i = (cin - 64) >> 1, t = (cin - 64) & 1;
            for (int k = 0; k < 12; k++)             // w11[o][i][k] * fil2[k][tap][t][u]
                s += w11[(o * 64 + i) * 12 + k] * fil2[((k * 9 + tap) * 2 + t) * 2 + u];
        }
    }
    F[idx] = s;
}

// ----------------------------------------------------------------- conv ----
// grid = (256 rows, 12 ocg) ; block = 256 threads (one per x).
__global__ __launch_bounds__(256) void conv_kernel(
    const float* __restrict__ x0, const float* __restrict__ x1,
    const float* __restrict__ F, const float* __restrict__ b0,
    float* __restrict__ out, float* __restrict__ mean_acc) {
    const int x   = threadIdx.x;
    const int y   = blockIdx.x;
    const int co0 = blockIdx.y * OCG;

    const int ym = (y == 0) ? NN - 1 : y - 1;
    const int yp = (y == NN - 1) ? 0 : y + 1;
    const int xm = (x == 0) ? NN - 1 : x - 1;
    const int xp = (x == NN - 1) ? 0 : x + 1;
    const int sy[3] = {ym, y, yp};
    const int sx[3] = {xm, x, xp};
    int off[9];
#pragma unroll
    for (int dy = 0; dy < 3; dy++)
#pragma unroll
        for (int dx = 0; dx < 3; dx++) off[dy * 3 + dx] = sy[dy] * NN + sx[dx];

    float acc[OCG];
#pragma unroll
    for (int i = 0; i < OCG; i++) acc[i] = 0.0f;

    for (int i = 0; i < 64; i++) {
        {   // x0 channel i  -> cin = i
            const float* p = x0 + (size_t)i * NPIX;
            float v[9];
#pragma unroll
            for (int j = 0; j < 9; j++) v[j] = p[off[j]];
            const float* Fp = F + ((size_t)co0 * CIN + i) * 9;
#pragma unroll
            for (int oc = 0; oc < OCG; oc++) {
                const float* f = Fp + (size_t)oc * CIN * 9;
                float s = acc[oc];
#pragma unroll
                for (int j = 0; j < 9; j++) s += f[j] * v[j];
                acc[oc] = s;
            }
        }
        {   // x1 channels (i,0),(i,1) -> cin = 64+2i, 64+2i+1 (interleaved pairs)
            const float2* p = (const float2*)(x1 + (size_t)i * (NPIX * 2));
            float2 v[9];
#pragma unroll
            for (int j = 0; j < 9; j++) v[j] = p[off[j]];
            const float* Fp = F + ((size_t)co0 * CIN + 64 + 2 * i) * 9;
#pragma unroll
            for (int oc = 0; oc < OCG; oc++) {
                const float* f = Fp + (size_t)oc * CIN * 9;
                float s = acc[oc];
#pragma unroll
                for (int j = 0; j < 9; j++) s += f[j] * v[j].x;
#pragma unroll
                for (int j = 0; j < 9; j++) s += f[9 + j] * v[j].y;
                acc[oc] = s;
            }
        }
    }

    // ------------------------------------------------------- epilogue ----
    __shared__ float red[OCG][4];
    const int wave = threadIdx.x >> 6;
    const int lane = threadIdx.x & 63;
    const bool isOut1 = (co0 >= 64);

#pragma unroll
    for (int oc = 0; oc < OCG; oc++) {
        int co = co0 + oc;
        if (!isOut1) {
            out[(size_t)co * NPIX + y * NN + x] = acc[oc] + b0[co];
        } else {
            int c1 = co - 64;
            int o = c1 >> 1, u = c1 & 1;
            out[(size_t)OUT1_OFF + ((size_t)o * NPIX + y * NN + x) * 2 + u] = acc[oc];
            float s = acc[oc];
#pragma unroll
            for (int d = 32; d > 0; d >>= 1) s += __shfl_down(s, d, 64);
            if (lane == 0) red[oc][wave] = s;
        }
    }
    if (isOut1) {
        __syncthreads();
        if (threadIdx.x < OCG) {
            float s = red[threadIdx.x][0] + red[threadIdx.x][1] +
                      red[threadIdx.x][2] + red[threadIdx.x][3];
            atomicAdd(&mean_acc[co0 - 64 + threadIdx.x], s);
        }
    }
}

// ------------------------------------------------------------- finalize ----
// out1[o][y][x][u] += (mean_acc[2o+u]/65536) * b1[o] ; vectorized over (pixel, u-pair).
__global__ void finalize_kernel(float* __restrict__ out, const float* __restrict__ mean_acc,
                                const float* __restrict__ b1) {
    int idx = blockIdx.x * 256 + threadIdx.x;          // float2 index
    if (idx >= NPIX * 64) return;
    int o = idx >> 16;                                  // 65536 float2 per o
    float bb = b1[o];
    float m0 = mean_acc[o * 2 + 0] * (1.0f / 65536.0f) * bb;
    float m1 = mean_acc[o * 2 + 1] * (1.0f / 65536.0f) * bb;
    float2* p = (float2*)(out + (size_t)OUT1_OFF) + idx;
    float2 v = *p;
    v.x += m0; v.y += m1;
    *p = v;
}

// --------------------------------------------------------------- launch ----
extern "C" void kernel_launch(void* const* d_in, const int* in_sizes, int n_in,
                              void* d_out, int out_size, void* d_ws, size_t ws_size,
                              hipStream_t stream) {
    const float* x0   = (const float*)d_in[0];
    const float* x1   = (const float*)d_in[1];
    const float* fil0 = (const float*)d_in[2];
    const float* fil1 = (const float*)d_in[3];
    const float* fil2 = (const float*)d_in[4];
    const float* w00  = (const float*)d_in[5];
    const float* w01  = (const float*)d_in[6];
    const float* w10  = (const float*)d_in[7];
    const float* w11  = (const float*)d_in[8];
    const float* b0   = (const float*)d_in[9];
    const float* b1   = (const float*)d_in[10];

    float* F        = (float*)d_ws;                                        // 1,327,104 B
    float* mean_acc = (float*)((char*)d_ws + (size_t)COUT * CIN * TAPS * 4); // 512 B
    float* out = (float*)d_out;

    synth_kernel<<<(COUT * CIN * TAPS + 255) / 256, 256, 0, stream>>>(
        fil0, fil1, fil2, w00, w01, w10, w11, F, mean_acc);

    dim3 grid(NN, COUT / OCG);
    conv_kernel<<<grid, 256, 0, stream>>>(x0, x1, F, b0, out, mean_acc);

    finalize_kernel<<<(NPIX * 64 + 255) / 256, 256, 0, stream>>>(out, mean_acc, b1);
}

// Round 3
// 313.688 us; speedup vs baseline: 4.6817x; 4.6817x over previous
//
#include <hip/hip_runtime.h>
#include <hip/hip_bf16.h>
#include <string.h>

// ConvContract via bf16 MFMA implicit GEMM.
// C[192 co][65536 px] = sum_k F[co][k] * X[k][px], k = (cin,tap), K=1728 (padded 1920).
// k layout: chunk = cin>>4 (12 chunks); within chunk kpos in [0,160): tap = kpos>>4 (9 real
// + pad taps 9 with F=0), cl = kpos&15 (cin low bits). Both A and B index k identically.
// out0 = C[0:64] + b0 ; out1 = C[64:192] (+ mean*b1 in apply kernel).

#define NN 256
#define NPIX 65536
#define OUT1_OFF 4194304      // 64*256*256
#define XS 20                 // cin stride (ushorts) in Xlds  (40B: 2/4-way banks max)
#define FS 164                // k stride (ushorts) in Flds    (328B: conflict-free-ish)

typedef __attribute__((ext_vector_type(8))) short short8;
typedef __attribute__((ext_vector_type(4))) float floatx4;

__device__ __forceinline__ unsigned short f2b(float x) {
    unsigned int u;
    memcpy(&u, &x, 4);
    unsigned int r = (u + 0x7FFFu + ((u >> 16) & 1u)) >> 16;   // RTNE
    return (unsigned short)r;
}

// ---------------------------------------------------------------- synth ----
// Fb[co][chunk][kpos] bf16, kpos = tap*16 + cl ; zero for tap == 9 (pad).
__global__ void synth_kernel(const float* __restrict__ fil0, const float* __restrict__ fil1,
                             const float* __restrict__ fil2,
                             const float* __restrict__ w00, const float* __restrict__ w01,
                             const float* __restrict__ w10, const float* __restrict__ w11,
                             unsigned short* __restrict__ Fb) {
    int idx = blockIdx.x * 256 + threadIdx.x;
    if (idx >= 192 * 12 * 160) return;
    int kpos  = idx % 160;
    int chunk = (idx / 160) % 12;
    int co    = idx / 1920;
    int tap = kpos >> 4, cl = kpos & 15;
    float s = 0.0f;
    if (tap < 9) {
        int cin = chunk * 16 + cl;
        if (co < 64) {
            if (cin < 64) {
                for (int k = 0; k < 3; k++)
                    s += w00[(co * 64 + cin) * 3 + k] * fil0[k * 9 + tap];
            } else {
                int i = (cin - 64) >> 1, t = (cin - 64) & 1;
                for (int k = 0; k < 6; k++)
                    s += w10[(co * 64 + i) * 6 + k] * fil1[(k * 9 + tap) * 2 + t];
            }
        } else {
            int o = (co - 64) >> 1, u = (co - 64) & 1;
            if (cin < 64) {
                for (int k = 0; k < 6; k++)
                    s += w01[(o * 64 + cin) * 6 + k] * fil1[(k * 9 + tap) * 2 + u];
            } else {
                int i = (cin - 64) >> 1, t = (cin - 64) & 1;
                for (int k = 0; k < 12; k++)
                    s += w11[(o * 64 + i) * 12 + k] * fil2[((k * 9 + tap) * 2 + t) * 2 + u];
            }
        }
    }
    Fb[idx] = f2b(s);
}

// ----------------------------------------------------------------- conv ----
// grid (256 y, 2 mtile), block 512 = 8 waves (2 wm x 4 wn); wave tile 48M x 64N.
__global__ __launch_bounds__(512, 4) void conv_kernel(
    const float* __restrict__ x0, const float* __restrict__ x1,
    const unsigned short* __restrict__ Fb, const float* __restrict__ b0,
    float* __restrict__ out, float* __restrict__ mean_partial) {

    __shared__ unsigned short Flds[96 * FS];        // 31488 B
    __shared__ unsigned short Xlds[3 * 258 * XS];   // 30960 B
    __shared__ float red[96][4];                    //  1536 B

    const int tid = threadIdx.x;
    const int y = blockIdx.x;
    const int mtile = blockIdx.y;
    const int m0 = mtile * 96;

    const int l = tid & 63, w = tid >> 6;
    const int wm = w >> 2, wn = w & 3;
    const int mw = wm * 48, nw = wn * 64;
    const int ln = l & 15, quad = l >> 4;

    // A fragment bases (ushort indices): m = mw + f*16 + ln, k-run at quad*8
    int baseA[3];
#pragma unroll
    for (int f = 0; f < 3; f++) baseA[f] = (mw + f * 16 + ln) * FS + quad * 8;
    // B fragment bases: col = nw + g*16 + ln
    int baseB[4];
#pragma unroll
    for (int g = 0; g < 4; g++) baseB[g] = (nw + g * 16 + ln) * XS;
    // per-K32-step B offsets: tap = 2*ks + (quad>>1); row/dx from tap; kh1 = quad&1
    int offB[5];
#pragma unroll
    for (int ks = 0; ks < 5; ks++) {
        int tap = 2 * ks + (quad >> 1);
        int row, dx;
        if (tap > 8) { row = 1; dx = 1; }            // pad tap: F=0, address harmless
        else { row = tap / 3; dx = tap - row * 3; }
        offB[ks] = (row * 258 + dx) * XS + (quad & 1) * 8;
    }

    floatx4 acc[3][4];
#pragma unroll
    for (int f = 0; f < 3; f++)
#pragma unroll
        for (int g = 0; g < 4; g++) acc[f][g] = (floatx4){0.f, 0.f, 0.f, 0.f};

    for (int c = 0; c < 12; c++) {
        // ---- stage F chunk: 96 rows x 160 k (bf16) ----
#pragma unroll
        for (int it = 0; it < 8; it++) {
            int idx = it * 512 + tid;
            if (idx < 3840) {
                int r = idx / 40;                    // 40 uint2 per row
                int g = idx - r * 40;
                uint2 v = *(const uint2*)(Fb + (((size_t)(m0 + r) * 12 + c) * 160 + g * 4));
                *(uint2*)(Flds + r * FS + g * 4) = v;
            }
        }
        // ---- stage X chunk: 16 cin x 3 rows x 258 cols, cin-innermost ----
        {
            // wave w handles slots w, w+8, ..., w+40 (slot = cin*3 + row)
#pragma unroll
            for (int s = 0; s < 6; s++) {
                int slot = w + 8 * s;
                int cl = slot / 3;
                int r = slot - 3 * cl;
                int cg = c * 16 + cl;
                int yr = (y + r + 255) & 255;
                const float* rowp;
                int stride;
                if (cg < 64) { rowp = x0 + ((size_t)(cg * 256 + yr)) * 256; stride = 1; }
                else {
                    int cc = cg - 64;
                    rowp = x1 + (((size_t)((cc >> 1) * 256 + yr)) * 256) * 2 + (cc & 1);
                    stride = 2;
                }
                unsigned short* dst = Xlds + r * 258 * XS + cl;
#pragma unroll
                for (int j = 0; j < 4; j++) {
                    int p = l + 64 * j;
                    int x = (p + 255) & 255;
                    dst[p * XS] = f2b(rowp[x * stride]);
                }
            }
            // edge cols p = 256, 257
            if (tid < 96) {
                int slot = tid >> 1;
                int p = 256 + (tid & 1);
                int cl = slot / 3;
                int r = slot - 3 * cl;
                int cg = c * 16 + cl;
                int yr = (y + r + 255) & 255;
                int x = (p + 255) & 255;
                float v;
                if (cg < 64) v = x0[((size_t)(cg * 256 + yr)) * 256 + x];
                else {
                    int cc = cg - 64;
                    v = x1[((((size_t)((cc >> 1) * 256 + yr)) * 256) + x) * 2 + (cc & 1)];
                }
                Xlds[(r * 258 + p) * XS + cl] = f2b(v);
            }
        }
        __syncthreads();

        // ---- compute: 5 K32 steps x (3 A-frags x 4 B-frags) ----
#pragma unroll
        for (int ks = 0; ks < 5; ks++) {
            short8 A[3], B[4];
#pragma unroll
            for (int f = 0; f < 3; f++) {
                int ia = baseA[f] + ks * 32;
                union { uint2 u[2]; short8 s; } t;
                t.u[0] = *(const uint2*)(Flds + ia);
                t.u[1] = *(const uint2*)(Flds + ia + 4);
                A[f] = t.s;
            }
#pragma unroll
            for (int g = 0; g < 4; g++) {
                int ib = baseB[g] + offB[ks];
                union { uint2 u[2]; short8 s; } t;
                t.u[0] = *(const uint2*)(Xlds + ib);
                t.u[1] = *(const uint2*)(Xlds + ib + 4);
                B[g] = t.s;
            }
#pragma unroll
            for (int f = 0; f < 3; f++)
#pragma unroll
                for (int g = 0; g < 4; g++)
                    acc[f][g] = __builtin_amdgcn_mfma_f32_16x16x32_bf16(A[f], B[g], acc[f][g], 0, 0, 0);
        }
        __syncthreads();
    }

    // ------------------------------------------------------- epilogue ----
    // C/D layout: col = ln, row(within 16) = quad*4 + reg.
#pragma unroll
    for (int f = 0; f < 3; f++) {
#pragma unroll
        for (int reg = 0; reg < 4; reg++) {
            float s = acc[f][0][reg] + acc[f][1][reg] + acc[f][2][reg] + acc[f][3][reg];
#pragma unroll
            for (int d = 1; d < 16; d <<= 1) s += __shfl_xor(s, d, 64);
            if (ln == 0) red[mw + f * 16 + quad * 4 + reg][wn] = s;
        }
    }
#pragma unroll
    for (int f = 0; f < 3; f++)
#pragma unroll
        for (int g = 0; g < 4; g++)
#pragma unroll
            for (int reg = 0; reg < 4; reg++) {
                int rowl = mw + f * 16 + quad * 4 + reg;
                int co = m0 + rowl;
                int col = nw + g * 16 + ln;
                float v = acc[f][g][reg];
                if (co < 64) {
                    out[(size_t)co * NPIX + y * NN + col] = v + b0[co];
                } else {
                    int c1 = co - 64, o = c1 >> 1, u = c1 & 1;
                    out[(size_t)OUT1_OFF + ((size_t)o * NPIX + y * NN + col) * 2 + u] = v;
                }
            }
    __syncthreads();
    if (tid < 96) {
        int co = m0 + tid;
        if (co >= 64) {
            float s = red[tid][0] + red[tid][1] + red[tid][2] + red[tid][3];
            mean_partial[y * 128 + (co - 64)] = s;    // disjoint per (y, mtile): no atomics
        }
    }
}

// ------------------------------------------------------------- reduce ----
// meanb[c1] = (sum_y mean_partial[y][c1]) / 65536 * b1[c1>>1]
__global__ void reduce_kernel(const float* __restrict__ mean_partial,
                              const float* __restrict__ b1, float* __restrict__ meanb) {
    int o = blockIdx.x;           // 64
    int t = threadIdx.x;          // 256
    float s0 = mean_partial[t * 128 + 2 * o];
    float s1 = mean_partial[t * 128 + 2 * o + 1];
#pragma unroll
    for (int d = 1; d < 64; d <<= 1) {
        s0 += __shfl_xor(s0, d, 64);
        s1 += __shfl_xor(s1, d, 64);
    }
    __shared__ float sh[2][4];
    if ((t & 63) == 0) { sh[0][t >> 6] = s0; sh[1][t >> 6] = s1; }
    __syncthreads();
    if (t == 0) {
        float S0 = sh[0][0] + sh[0][1] + sh[0][2] + sh[0][3];
        float S1 = sh[1][0] + sh[1][1] + sh[1][2] + sh[1][3];
        float scale = b1[o] * (1.0f / 65536.0f);
        meanb[2 * o] = S0 * scale;
        meanb[2 * o + 1] = S1 * scale;
    }
}

// -------------------------------------------------------------- apply ----
__global__ void apply_kernel(float* __restrict__ out, const float* __restrict__ meanb) {
    int idx = blockIdx.x * 256 + threadIdx.x;     // float2 index over out1
    int o = idx >> 16;
    float2* p = (float2*)(out + OUT1_OFF) + idx;
    float2 v = *p;
    v.x += meanb[2 * o];
    v.y += meanb[2 * o + 1];
    *p = v;
}

// --------------------------------------------------------------- launch ----
extern "C" void kernel_launch(void* const* d_in, const int* in_sizes, int n_in,
                              void* d_out, int out_size, void* d_ws, size_t ws_size,
                              hipStream_t stream) {
    const float* x0   = (const float*)d_in[0];
    const float* x1   = (const float*)d_in[1];
    const float* fil0 = (const float*)d_in[2];
    const float* fil1 = (const float*)d_in[3];
    const float* fil2 = (const float*)d_in[4];
    const float* w00  = (const float*)d_in[5];
    const float* w01  = (const float*)d_in[6];
    const float* w10  = (const float*)d_in[7];
    const float* w11  = (const float*)d_in[8];
    const float* b0   = (const float*)d_in[9];
    const float* b1   = (const float*)d_in[10];

    unsigned short* Fb = (unsigned short*)d_ws;                    // 737280 B
    float* mean_partial = (float*)((char*)d_ws + 737280);          // 131072 B
    float* meanb        = (float*)((char*)d_ws + 737280 + 131072); // 512 B
    float* out = (float*)d_out;

    synth_kernel<<<(192 * 12 * 160 + 255) / 256, 256, 0, stream>>>(
        fil0, fil1, fil2, w00, w01, w10, w11, Fb);

    dim3 grid(NN, 2);
    conv_kernel<<<grid, 512, 0, stream>>>(x0, x1, Fb, b0, out, mean_partial);

    reduce_kernel<<<64, 256, 0, stream>>>(mean_partial, b1, meanb);

    apply_kernel<<<NPIX * 64 / 256, 256, 0, stream>>>(out, meanb);
}

// Round 4
// 175.095 us; speedup vs baseline: 8.3874x; 1.7915x over previous
//
#include <hip/hip_runtime.h>
#include <hip/hip_bf16.h>
#include <string.h>

// ConvContract via bf16 MFMA implicit GEMM, async-staged.
// C[192 co][65536 px] = sum_k F[co][k] * X[k][px], k=(cin,tap), K=1728 (pad 1920).
// k layout: chunk = cin>>4 (12); kpos = tap*16 + cl (taps 0..8 real, 9 = zero pad).
// Xb[y][chunk][x][cl] bf16 (prep kernel) ; Fb[chunk][co][kpos] bf16 (synth kernel).
// out0 = C[0:64] + b0 ; out1 = C[64:192] + mean*b1 (reduce+apply kernels).

#define NN 256
#define NPIX 65536
#define OUT1_OFF 4194304

typedef __attribute__((ext_vector_type(8))) short short8;
typedef __attribute__((ext_vector_type(4))) float floatx4;

__device__ __forceinline__ unsigned short f2b(float x) {
    unsigned int u; memcpy(&u, &x, 4);
    return (unsigned short)((u + 0x7FFFu + ((u >> 16) & 1u)) >> 16);   // RTNE
}

// ----------------------------------------------------------------- prep ----
// Xb[y][c][x][cl] = bf16( X[cin=16c+cl][y][x] ) ; grid (256 y, 12 c), block 256 (t=x).
__global__ __launch_bounds__(256) void prep_kernel(const float* __restrict__ x0,
                                                   const float* __restrict__ x1,
                                                   unsigned short* __restrict__ Xb) {
    const int x = threadIdx.x;
    const int y = blockIdx.x;
    const int c = blockIdx.y;
    unsigned int u[8];
    if (c < 4) {
        const float* base = x0 + ((size_t)c * 16) * NPIX + y * NN + x;
#pragma unroll
        for (int j = 0; j < 8; j++) {
            unsigned short a = f2b(base[(size_t)(2 * j) * NPIX]);
            unsigned short b = f2b(base[(size_t)(2 * j + 1) * NPIX]);
            u[j] = (unsigned int)a | ((unsigned int)b << 16);
        }
    } else {
        const float2* base = (const float2*)x1 + ((size_t)(8 * (c - 4))) * NPIX + y * NN + x;
#pragma unroll
        for (int j = 0; j < 8; j++) {
            float2 v = base[(size_t)j * NPIX];
            u[j] = (unsigned int)f2b(v.x) | ((unsigned int)f2b(v.y) << 16);
        }
    }
    uint4* dst = (uint4*)(Xb + (((size_t)y * 12 + c) * 256 + x) * 16);
    dst[0] = make_uint4(u[0], u[1], u[2], u[3]);
    dst[1] = make_uint4(u[4], u[5], u[6], u[7]);
}

// ---------------------------------------------------------------- synth ----
// Fb[c][co][kpos] bf16, kpos = tap*16 + cl ; zero for tap == 9 (pad).
__global__ void synth_kernel(const float* __restrict__ fil0, const float* __restrict__ fil1,
                             const float* __restrict__ fil2,
                             const float* __restrict__ w00, const float* __restrict__ w01,
                             const float* __restrict__ w10, const float* __restrict__ w11,
                             unsigned short* __restrict__ Fb) {
    int idx = blockIdx.x * 256 + threadIdx.x;
    if (idx >= 12 * 192 * 160) return;
    int kpos = idx % 160;
    int co   = (idx / 160) % 192;
    int c    = idx / (160 * 192);
    int tap = kpos >> 4, cl = kpos & 15;
    float s = 0.0f;
    if (tap < 9) {
        int cin = c * 16 + cl;
        if (co < 64) {
            if (cin < 64) {
                for (int k = 0; k < 3; k++)
                    s += w00[(co * 64 + cin) * 3 + k] * fil0[k * 9 + tap];
            } else {
                int i = (cin - 64) >> 1, t = (cin - 64) & 1;
                for (int k = 0; k < 6; k++)
                    s += w10[(co * 64 + i) * 6 + k] * fil1[(k * 9 + tap) * 2 + t];
            }
        } else {
            int o = (co - 64) >> 1, u = (co - 64) & 1;
            if (cin < 64) {
                for (int k = 0; k < 6; k++)
                    s += w01[(o * 64 + cin) * 6 + k] * fil1[(k * 9 + tap) * 2 + u];
            } else {
                int i = (cin - 64) >> 1, t = (cin - 64) & 1;
                for (int k = 0; k < 12; k++)
                    s += w11[(o * 64 + i) * 12 + k] * fil2[((k * 9 + tap) * 2 + t) * 2 + u];
            }
        }
    }
    Fb[idx] = f2b(s);
}

// ----------------------------------------------------------------- conv ----
// grid (256 y, 2 mtile), block 512 = 8 waves (2 wm x 4 wn); wave tile 48M x 64N.
__global__ __launch_bounds__(512, 4) void conv_kernel(
    const unsigned short* __restrict__ Xb, const unsigned short* __restrict__ Fb,
    const float* __restrict__ b0, float* __restrict__ out,
    float* __restrict__ mean_partial) {

    __shared__ __align__(16) unsigned short Flds[96 * 160];   // 30720 B
    __shared__ __align__(16) unsigned short Xlds[3 * 256 * 16]; // 24576 B
    __shared__ float red[96][4];                               //  1536 B

    const int tid = threadIdx.x;
    const int y = blockIdx.x;
    const int m0 = blockIdx.y * 96;
    const int l = tid & 63, w = tid >> 6;
    const int wm = w >> 2, wn = w & 3;
    const int mw = wm * 48, nw = wn * 64;
    const int ln = l & 15, quad = l >> 4;

    // A fragment bases (ushort idx): row (mw+f*16+ln), k-run at quad*8
    int baseA[3];
#pragma unroll
    for (int f = 0; f < 3; f++) baseA[f] = (mw + f * 16 + ln) * 160 + quad * 8;
    // B column bases and per-K32-step row/half offsets + dx
    int cb[4];
#pragma unroll
    for (int g = 0; g < 4; g++) cb[g] = nw + g * 16 + ln;
    int rofs[5], dxv[5];
#pragma unroll
    for (int ks = 0; ks < 5; ks++) {
        int tap = 2 * ks + (quad >> 1);
        int r, dx;
        if (tap > 8) { r = 0; dx = 0; }            // pad tap: F=0, address harmless
        else { r = tap / 3; dx = tap - 3 * r - 1; }
        rofs[ks] = r * 4096 + (quad & 1) * 8;
        dxv[ks] = dx;
    }

    floatx4 acc[3][4];
#pragma unroll
    for (int f = 0; f < 3; f++)
#pragma unroll
        for (int g = 0; g < 4; g++) acc[f][g] = (floatx4){0.f, 0.f, 0.f, 0.f};

    for (int c = 0; c < 12; c++) {
        // ---- async stage: F (30 segs x 1KB) + X (24 segs x 1KB) ----
        const unsigned short* FbC = Fb + ((size_t)c * 192 + m0) * 160;
        for (int s = w; s < 54; s += 8) {
            const unsigned short* g;
            unsigned short* lb;
            if (s < 30) {
                g = FbC + s * 512;
                lb = Flds + s * 512;
            } else {
                int j = s - 30;
                int r = j >> 3, p = j & 7;
                int yr = (y + r + 255) & 255;
                g = Xb + (((size_t)yr * 12 + c) * 4096) + p * 512;
                lb = Xlds + r * 4096 + p * 512;
            }
            __builtin_amdgcn_global_load_lds(
                (const __attribute__((address_space(1))) unsigned int*)(g + l * 8),
                (__attribute__((address_space(3))) unsigned int*)lb, 16, 0, 0);
        }
        __syncthreads();

        // ---- compute: 5 K32 steps x (3 A x 4 B) ----
#pragma unroll
        for (int ks = 0; ks < 5; ks++) {
            short8 A[3], B[4];
#pragma unroll
            for (int f = 0; f < 3; f++)
                A[f] = *(const short8*)(Flds + baseA[f] + ks * 32);
#pragma unroll
            for (int g = 0; g < 4; g++) {
                int colw = (cb[g] + dxv[ks]) & 255;
                B[g] = *(const short8*)(Xlds + rofs[ks] + colw * 16);
            }
#pragma unroll
            for (int f = 0; f < 3; f++)
#pragma unroll
                for (int g = 0; g < 4; g++)
                    acc[f][g] = __builtin_amdgcn_mfma_f32_16x16x32_bf16(A[f], B[g], acc[f][g], 0, 0, 0);
        }
        __syncthreads();
    }

    // ------------------------------------------------------- epilogue ----
    // C/D layout: col = ln, row(within 16) = quad*4 + reg.
#pragma unroll
    for (int f = 0; f < 3; f++)
#pragma unroll
        for (int reg = 0; reg < 4; reg++) {
            float s = acc[f][0][reg] + acc[f][1][reg] + acc[f][2][reg] + acc[f][3][reg];
#pragma unroll
            for (int d = 1; d < 16; d <<= 1) s += __shfl_xor(s, d, 64);
            if (ln == 0) red[mw + f * 16 + quad * 4 + reg][wn] = s;
        }

#pragma unroll
    for (int f = 0; f < 3; f++) {
        int cob = m0 + mw + f * 16 + quad * 4;
#pragma unroll
        for (int g = 0; g < 4; g++) {
            int col = nw + g * 16 + ln;
            if (cob < 64) {
#pragma unroll
                for (int reg = 0; reg < 4; reg++)
                    out[(size_t)(cob + reg) * NPIX + y * NN + col] = acc[f][g][reg] + b0[cob + reg];
            } else {
#pragma unroll
                for (int reg = 0; reg < 4; reg += 2) {
                    int o = (cob + reg - 64) >> 1;
                    float2 v = make_float2(acc[f][g][reg], acc[f][g][reg + 1]);
                    *((float2*)(out + OUT1_OFF) + ((size_t)o * NPIX + y * NN + col)) = v;
                }
            }
        }
    }
    __syncthreads();
    if (tid < 96) {
        int co = m0 + tid;
        if (co >= 64) {
            float s = red[tid][0] + red[tid][1] + red[tid][2] + red[tid][3];
            mean_partial[y * 128 + (co - 64)] = s;   // disjoint per (y,mtile): no atomics
        }
    }
}

// ------------------------------------------------------------- reduce ----
__global__ void reduce_kernel(const float* __restrict__ mean_partial,
                              const float* __restrict__ b1, float* __restrict__ meanb) {
    int o = blockIdx.x;           // 64
    int t = threadIdx.x;          // 256
    float s0 = mean_partial[t * 128 + 2 * o];
    float s1 = mean_partial[t * 128 + 2 * o + 1];
#pragma unroll
    for (int d = 1; d < 64; d <<= 1) {
        s0 += __shfl_xor(s0, d, 64);
        s1 += __shfl_xor(s1, d, 64);
    }
    __shared__ float sh[2][4];
    if ((t & 63) == 0) { sh[0][t >> 6] = s0; sh[1][t >> 6] = s1; }
    __syncthreads();
    if (t == 0) {
        float S0 = sh[0][0] + sh[0][1] + sh[0][2] + sh[0][3];
        float S1 = sh[1][0] + sh[1][1] + sh[1][2] + sh[1][3];
        float scale = b1[o] * (1.0f / 65536.0f);
        meanb[2 * o] = S0 * scale;
        meanb[2 * o + 1] = S1 * scale;
    }
}

// -------------------------------------------------------------- apply ----
__global__ void apply_kernel(float* __restrict__ out, const float* __restrict__ meanb) {
    int idx = blockIdx.x * 256 + threadIdx.x;     // float2 index over out1
    int o = idx >> 16;
    float2* p = (float2*)(out + OUT1_OFF) + idx;
    float2 v = *p;
    v.x += meanb[2 * o];
    v.y += meanb[2 * o + 1];
    *p = v;
}

// --------------------------------------------------------------- launch ----
extern "C" void kernel_launch(void* const* d_in, const int* in_sizes, int n_in,
                              void* d_out, int out_size, void* d_ws, size_t ws_size,
                              hipStream_t stream) {
    const float* x0   = (const float*)d_in[0];
    const float* x1   = (const float*)d_in[1];
    const float* fil0 = (const float*)d_in[2];
    const float* fil1 = (const float*)d_in[3];
    const float* fil2 = (const float*)d_in[4];
    const float* w00  = (const float*)d_in[5];
    const float* w01  = (const float*)d_in[6];
    const float* w10  = (const float*)d_in[7];
    const float* w11  = (const float*)d_in[8];
    const float* b0   = (const float*)d_in[9];
    const float* b1   = (const float*)d_in[10];

    unsigned short* Xb  = (unsigned short*)d_ws;                       // 25,165,824 B
    unsigned short* Fb  = (unsigned short*)((char*)d_ws + 25165824);   //    737,280 B
    float* mean_partial = (float*)((char*)d_ws + 25903104);            //    131,072 B
    float* meanb        = (float*)((char*)d_ws + 26034176);            //        512 B
    float* out = (float*)d_out;

    prep_kernel<<<dim3(NN, 12), 256, 0, stream>>>(x0, x1, Xb);

    synth_kernel<<<(12 * 192 * 160 + 255) / 256, 256, 0, stream>>>(
        fil0, fil1, fil2, w00, w01, w10, w11, Fb);

    conv_kernel<<<dim3(NN, 2), 512, 0, stream>>>(Xb, Fb, b0, out, mean_partial);

    reduce_kernel<<<64, 256, 0, stream>>>(mean_partial, b1, meanb);

    apply_kernel<<<NPIX * 64 / 256, 256, 0, stream>>>(out, meanb);
}